// Round 3
// baseline (203.344 us; speedup 1.0000x reference)
//
#include <hip/hip_runtime.h>
#include <math.h>

#define BATCH 256
#define DIN   5120
#define RANK  160
#define NS    16
#define NCAT  192   // RANK + NS + NS
#define BQ    8     // batches per k2 block

// ---------------------------------------------------------------------------
// k1: [P | Bp | C] = x(256x5120) @ [W_delta(5120x160) | W_B(5120x16) | W_C(5120x16)]
// Split-K (20 chunks of 256), 64x64 block tile, 4x4 register tile/thread,
// atomicAdd into pre-zeroed ws buffers. ~6-8 us, VALU/LDS-bound.
// ---------------------------------------------------------------------------
__global__ __launch_bounds__(256) void k1_gemm(
    const float* __restrict__ x, const float* __restrict__ Wd,
    const float* __restrict__ WB, const float* __restrict__ WC,
    float* __restrict__ P, float* __restrict__ Bp, float* __restrict__ Cc)
{
    __shared__ float xT[32][64];   // [k][m]
    __shared__ float Wt[32][64];   // [k][n]
    const int t  = threadIdx.x;
    const int m0 = blockIdx.x * 64;
    const int n0 = blockIdx.y * 64;
    const int k0 = blockIdx.z * 256;
    const int tm = (t >> 4) * 4;
    const int tn = (t & 15) * 4;

    const int lm  = t >> 2;
    const int lk  = (t & 3) * 8;
    const int ln  = t & 63;
    const int lkb = (t >> 6) * 8;

    const float* wsrc; int wstr;
    {
        const int c = n0 + ln;
        if (c < RANK)            { wsrc = Wd + c;                wstr = RANK; }
        else if (c < RANK + NS)  { wsrc = WB + (c - RANK);       wstr = NS;   }
        else                     { wsrc = WC + (c - RANK - NS);  wstr = NS;   }
    }

    float acc[4][4] = {{0.f}};

    for (int ks = 0; ks < 8; ++ks) {
        const int kb = k0 + ks * 32;
        {
            const float* src = x + (size_t)(m0 + lm) * DIN + kb + lk;
            const float4 a0 = *(const float4*)src;
            const float4 a1 = *(const float4*)(src + 4);
            xT[lk+0][lm]=a0.x; xT[lk+1][lm]=a0.y; xT[lk+2][lm]=a0.z; xT[lk+3][lm]=a0.w;
            xT[lk+4][lm]=a1.x; xT[lk+5][lm]=a1.y; xT[lk+6][lm]=a1.z; xT[lk+7][lm]=a1.w;
        }
        {
            const float* wp = wsrc + (size_t)(kb + lkb) * wstr;
            #pragma unroll
            for (int i = 0; i < 8; ++i) { Wt[lkb + i][ln] = *wp; wp += wstr; }
        }
        __syncthreads();
        #pragma unroll
        for (int k = 0; k < 32; ++k) {
            const float4 a = *(const float4*)&xT[k][tm];
            const float4 b = *(const float4*)&Wt[k][tn];
            acc[0][0] += a.x*b.x; acc[0][1] += a.x*b.y; acc[0][2] += a.x*b.z; acc[0][3] += a.x*b.w;
            acc[1][0] += a.y*b.x; acc[1][1] += a.y*b.y; acc[1][2] += a.y*b.z; acc[1][3] += a.y*b.w;
            acc[2][0] += a.z*b.x; acc[2][1] += a.z*b.y; acc[2][2] += a.z*b.z; acc[2][3] += a.z*b.w;
            acc[3][0] += a.w*b.x; acc[3][1] += a.w*b.y; acc[3][2] += a.w*b.z; acc[3][3] += a.w*b.w;
        }
        __syncthreads();
    }

    #pragma unroll
    for (int i = 0; i < 4; ++i) {
        const int gm = m0 + tm + i;
        #pragma unroll
        for (int j = 0; j < 4; ++j) {
            const int c = n0 + tn + j;
            float* dst;
            if (c < RANK)           dst = P  + gm * RANK + c;
            else if (c < RANK + NS) dst = Bp + gm * NS + (c - RANK);
            else                    dst = Cc + gm * NS + (c - RANK - NS);
            atomicAdd(dst, acc[i][j]);
        }
    }
}

__device__ __forceinline__ float softplus20(float z)
{
    if (z > 20.f) return z;
    return fmaxf(z, 0.f) + log1pf(__expf(-fabsf(z)));
}

// ---------------------------------------------------------------------------
// k2: fused dt-GEMM + SSM update + readout.
// Block = BQ(8) batches x 256 d-channels; grid (20, 32).
// dt from P (LDS broadcast) x Wdt columns (coalesced, 8 FMA per L2 load).
// A2 = -exp(A_log)*log2e once per d -> inner abar = exp2(dt*A2) (1 mul+1 exp).
// h read (84 MB) is the HBM floor: ~13 us.
// ---------------------------------------------------------------------------
__global__ __launch_bounds__(256) void k2_fused(
    const float* __restrict__ P, const float* __restrict__ Wdt,
    const float* __restrict__ bdt, const float* __restrict__ x,
    const float* __restrict__ h, const float* __restrict__ A_log,
    const float* __restrict__ Bp, const float* __restrict__ Cc,
    const float* __restrict__ Dv, float* __restrict__ y)
{
    __shared__ float sP[BQ][RANK];
    __shared__ float sB[BQ][NS];
    __shared__ float sC[BQ][NS];

    const int tid = threadIdx.x;
    const int d   = blockIdx.x * 256 + tid;   // 20 tiles
    const int b0  = blockIdx.y * BQ;          // 32 octets

    for (int i = tid; i < BQ * RANK; i += 256)
        sP[i / RANK][i % RANK] = P[(size_t)b0 * RANK + i];
    if (tid < BQ * NS)                sB[tid >> 4][tid & 15] = Bp[b0 * NS + tid];
    else if (tid < 2 * BQ * NS) { int u = tid - BQ * NS; sC[u >> 4][u & 15] = Cc[b0 * NS + u]; }
    __syncthreads();

    // dt for BQ batches: dot(P[b,:], Wdt[:,d]) over K=160
    float acc[BQ];
    #pragma unroll
    for (int b = 0; b < BQ; ++b) acc[b] = 0.f;
    const float* wcol = Wdt + d;
    #pragma unroll 4
    for (int k = 0; k < RANK; ++k) {
        const float w = wcol[(size_t)k * DIN];
        #pragma unroll
        for (int b = 0; b < BQ; ++b) acc[b] += sP[b][k] * w;
    }
    const float bb = bdt[d];
    float dt[BQ];
    #pragma unroll
    for (int b = 0; b < BQ; ++b) dt[b] = softplus20(acc[b] + bb);

    // A2 = -exp(A_log[d,:]) * log2(e), once per d
    float A2[NS];
    {
        const float4* ap = (const float4*)(A_log + (size_t)d * NS);
        #pragma unroll
        for (int q = 0; q < 4; ++q) {
            const float4 a4 = ap[q];
            A2[4*q+0] = -1.442695041f * __expf(a4.x);
            A2[4*q+1] = -1.442695041f * __expf(a4.y);
            A2[4*q+2] = -1.442695041f * __expf(a4.z);
            A2[4*q+3] = -1.442695041f * __expf(a4.w);
        }
    }
    const float dv = Dv[d];

    #pragma unroll 2
    for (int b = 0; b < BQ; ++b) {
        const int gb = b0 + b;
        const float dtv = dt[b];
        const float xv  = x[(size_t)gb * DIN + d];
        const float dtx = dtv * xv;
        const float4* hp = (const float4*)(h + ((size_t)gb * DIN + d) * NS);
        float s = 0.f;
        #pragma unroll
        for (int q = 0; q < 4; ++q) {
            const float4 h4 = hp[q];
            s += (exp2f(dtv * A2[4*q+0]) * h4.x + dtx * sB[b][4*q+0]) * sC[b][4*q+0];
            s += (exp2f(dtv * A2[4*q+1]) * h4.y + dtx * sB[b][4*q+1]) * sC[b][4*q+1];
            s += (exp2f(dtv * A2[4*q+2]) * h4.z + dtx * sB[b][4*q+2]) * sC[b][4*q+2];
            s += (exp2f(dtv * A2[4*q+3]) * h4.w + dtx * sB[b][4*q+3]) * sC[b][4*q+3];
        }
        y[(size_t)gb * DIN + d] = s + xv * dv;
    }
}

// ---------------------------------------------------------------------------
extern "C" void kernel_launch(void* const* d_in, const int* in_sizes, int n_in,
                              void* d_out, int out_size, void* d_ws, size_t ws_size,
                              hipStream_t stream)
{
    const float* x     = (const float*)d_in[0];
    const float* h     = (const float*)d_in[1];
    const float* Wd    = (const float*)d_in[2];
    const float* Wdt   = (const float*)d_in[3];
    const float* bdt   = (const float*)d_in[4];
    const float* A_log = (const float*)d_in[5];
    const float* WB    = (const float*)d_in[6];
    const float* WC    = (const float*)d_in[7];
    const float* Dv    = (const float*)d_in[8];
    float* out = (float*)d_out;

    // ws layout (floats): P (256x160) | Bp (256x16) | C (256x16)
    float* ws  = (float*)d_ws;
    float* P   = ws;
    float* Bp  = ws + BATCH * RANK;
    float* Cc  = Bp + BATCH * NS;

    hipMemsetAsync(ws, 0, (size_t)BATCH * NCAT * sizeof(float), stream);

    k1_gemm <<<dim3(4, 3, 20),        256, 0, stream>>>(x, Wd, WB, WC, P, Bp, Cc);
    k2_fused<<<dim3(20, BATCH / BQ),  256, 0, stream>>>(P, Wdt, bdt, x, h, A_log, Bp, Cc, Dv, out);
}